// Round 12
// baseline (194.215 us; speedup 1.0000x reference)
//
#include <hip/hip_runtime.h>
#include <hip/hip_fp16.h>

#define P_PLANE (1080*1920)          // 2,073,600 pixels per channel plane
#define LUT_C   35937                 // 33*33*33, per-channel LUT stride
#define N_IMG   4
#define SMEM_WORDS 35937
#define SMEM_BYTES (SMEM_WORDS * 4)   // 143,748 B of LDS
#define QPI     (P_PLANE / 4)         // 518,400 quads per image
#define TOTALQ  (N_IMG * QPI)         // 2,073,600 quads

typedef float fvec4 __attribute__((ext_vector_type(4)));   // builtin-compatible float4

__device__ __forceinline__ float ub0(unsigned int e) { return (float)(e & 255u); }
__device__ __forceinline__ float ub1(unsigned int e) { return (float)((e >> 8) & 255u); }
__device__ __forceinline__ float ub2(unsigned int e) { return (float)((e >> 16) & 255u); }

// ---------------------------------------------------------------------------
// Build linear u8 table in ws: entry i (= b*1089+g*33+r) packs (r,g,b,0) u8.
// 35937 entries * 4B = 140.4 KB. Quantization err <= 1/510 ~ 2e-3.
// ---------------------------------------------------------------------------
__global__ __launch_bounds__(256) void build_lin_u8(const float* __restrict__ lut,
                                                    unsigned int* __restrict__ T) {
    int i = blockIdx.x * blockDim.x + threadIdx.x;
    if (i >= LUT_C) return;
    unsigned int r = (unsigned int)__float2int_rn(lut[i] * 255.0f);
    unsigned int g = (unsigned int)__float2int_rn(lut[LUT_C + i] * 255.0f);
    unsigned int b = (unsigned int)__float2int_rn(lut[2 * LUT_C + i] * 255.0f);
    T[i] = r | (g << 8) | (b << 16);
}

__device__ __forceinline__ size_t quad_addr(int q) {
    int n = q / QPI;
    return (size_t)n * (3 * P_PLANE) + (size_t)(q - n * QPI) * 4;
}

// ---------------------------------------------------------------------------
// R11 pipeline body (resubmitted — previous round was a broker failure; the
// experiment never ran): processes quad qc whose inputs sit in (RS,GS,BS) —
// loaded TWO bodies ago — then immediately re-loads (RS,GS,BS) with quad
// qn+G for consumption two bodies later. No register rotate-copies: the two
// call sites bind distinct named register sets, so the vmcnt wait at Phase A
// covers only loads issued two full compute bodies earlier (R5/R10's bottom
// rotate forced a wait on loads only ~600cy old — the last unablated stall,
// synchronized across the 4-wave convoy per SIMD).
// Returns false (after storing) when there is no next quad.
// ---------------------------------------------------------------------------
__device__ __forceinline__ bool lut_body(const float* __restrict__ x,
                                         float* __restrict__ out,
                                         const unsigned int* s_lut,
                                         int& qc, size_t& bc,
                                         int& qn, size_t& bn,
                                         fvec4& RS, fvec4& GS, fvec4& BS,
                                         int G) {
    const float inv = (float)(1.0 / (1.000001 / 32.0));   // matches reference f32 rounding
    const float qs = 1.0f / 255.0f;                        // u8 dequant, folded into wb

    // ---- Phase A: idx + fracs for 4 pixels (consumes 2-body-old loads).
    int   idx[4];
    float fr[4], fg[4], fb[4];
#pragma unroll
    for (int i = 0; i < 4; ++i) {
        float tr = RS[i] * inv, tg = GS[i] * inv, tb = BS[i] * inv;
        float fr_ = floorf(tr), fg_ = floorf(tg), fb_ = floorf(tb);
        fr[i] = tr - fr_; fg[i] = tg - fg_; fb[i] = tb - fb_;   // fracs BEFORE clip
        int ri = min(max((int)fr_, 0), 31);
        int gi = min(max((int)fg_, 0), 31);
        int bi = min(max((int)fb_, 0), 31);
        idx[i] = bi * 1089 + gi * 33 + ri;
    }

    // ---- Phase B: issue all 16 ds_read2-class gathers.
    unsigned int e[4][8];
#pragma unroll
    for (int i = 0; i < 4; ++i) {
        int i0 = idx[i];
        int i1 = idx[i] + 1089;
        e[i][0] = s_lut[i0];       e[i][1] = s_lut[i0 + 1];
        e[i][2] = s_lut[i0 + 33];  e[i][3] = s_lut[i0 + 34];
        e[i][4] = s_lut[i1];       e[i][5] = s_lut[i1 + 1];
        e[i][6] = s_lut[i1 + 33];  e[i][7] = s_lut[i1 + 34];
    }

    // ---- Phase C: re-load THIS body's register set with quad qn+G
    // (consumed two bodies from now). Clamp to qc on tail (L1-hot, unused).
    int qp = qn + G;
    int qpc = (qp < TOTALQ) ? qp : qc;
    size_t bp = quad_addr(qpc);
    RS = *(const fvec4*)(x + bp);
    GS = *(const fvec4*)(x + bp + P_PLANE);
    BS = *(const fvec4*)(x + bp + 2 * P_PLANE);

    // ---- FENCE: issue phases above, consume phases below.
    __builtin_amdgcn_sched_barrier(0);

    // ---- Phase D: weights (pure VALU, fills the DS shadow).
    float w[4][8];
#pragma unroll
    for (int i = 0; i < 4; ++i) {
        float wr1 = fr[i], wr0 = 1.0f - fr[i];
        float wg1 = fg[i], wg0 = 1.0f - fg[i];
        float wb1 = fb[i] * qs, wb0 = (1.0f - fb[i]) * qs;   // fold 1/255
        float w00 = wb0 * wg0, w01 = wb0 * wg1, w10 = wb1 * wg0, w11 = wb1 * wg1;
        w[i][0] = w00 * wr0; w[i][1] = w00 * wr1;
        w[i][2] = w01 * wr0; w[i][3] = w01 * wr1;
        w[i][4] = w10 * wr0; w[i][5] = w10 * wr1;
        w[i][6] = w11 * wr0; w[i][7] = w11 * wr1;
    }

    // ---- Phase E: interpolate (ONE lgkm wait, then 96 FMAs).
    fvec4 vR, vG, vB;
#pragma unroll
    for (int i = 0; i < 4; ++i) {
        float aR = w[i][0] * ub0(e[i][0]);
        float aG = w[i][0] * ub1(e[i][0]);
        float aB = w[i][0] * ub2(e[i][0]);
#pragma unroll
        for (int k = 1; k < 8; ++k) {
            aR = fmaf(w[i][k], ub0(e[i][k]), aR);
            aG = fmaf(w[i][k], ub1(e[i][k]), aG);
            aB = fmaf(w[i][k], ub2(e[i][k]), aB);
        }
        vR[i] = aR; vG[i] = aG; vB[i] = aB;
    }

    // ---- Phase F: coalesced plain stores (1KB/wave each); data regs are
    // body-local -> redefined two bodies later (deferred-store aging free).
    *(fvec4*)(out + bc)               = vR;
    *(fvec4*)(out + bc + P_PLANE)     = vG;
    *(fvec4*)(out + bc + 2 * P_PLANE) = vB;

    if (qn >= TOTALQ) return false;
    qc = qn; bc = bn; qn = qp; bn = bp;   // qn stays UNclamped for termination
    return true;
}

// ---------------------------------------------------------------------------
// R11 main kernel: full LUT (u8x4) in LDS; 2-deep ping-pong pipeline with
// two named register sets (A/B) and zero rotate-copies.
// ---------------------------------------------------------------------------
__global__ __launch_bounds__(1024, 4) void apply_lut_lds(const float* __restrict__ x,
                                                         const unsigned int* __restrict__ T,
                                                         float* __restrict__ out) {
    extern __shared__ unsigned int s_lut[];
    const int tid = threadIdx.x;

    // Fill LDS: 8984 uint4 + 1 tail word, coalesced.
    {
        const uint4* Tv = (const uint4*)T;
        uint4* sv = (uint4*)s_lut;
        for (int i = tid; i < SMEM_WORDS / 4; i += blockDim.x) sv[i] = Tv[i];
        if (tid == 0) s_lut[SMEM_WORDS - 1] = T[SMEM_WORDS - 1];
    }
    __syncthreads();

    const int G = gridDim.x * blockDim.x;      // 262,144

    int qc = blockIdx.x * blockDim.x + tid;
    if (qc >= TOTALQ) return;

    // ---- Prologue: load set A (current) and set B (next, clamped if absent).
    size_t bc = quad_addr(qc);
    fvec4 rA = *(const fvec4*)(x + bc);
    fvec4 gA = *(const fvec4*)(x + bc + P_PLANE);
    fvec4 bA = *(const fvec4*)(x + bc + 2 * P_PLANE);

    int qn = qc + G;                            // real (unclamped) next index
    size_t bn = quad_addr((qn < TOTALQ) ? qn : qc);
    fvec4 rB = *(const fvec4*)(x + bn);
    fvec4 gB = *(const fvec4*)(x + bn + P_PLANE);
    fvec4 bB = *(const fvec4*)(x + bn + 2 * P_PLANE);

    while (true) {
        if (!lut_body(x, out, s_lut, qc, bc, qn, bn, rA, gA, bA, G)) break;
        if (!lut_body(x, out, s_lut, qc, bc, qn, bn, rB, gB, bB, G)) break;
    }
}

// ===========================================================================
// Fallback path (R0, proven): fp16 cell-duplicated table + global gathers.
// ===========================================================================
__global__ __launch_bounds__(256) void build_table(const float* __restrict__ lut,
                                                   uint4* __restrict__ T) {
    int cell = blockIdx.x * blockDim.x + threadIdx.x;   // 0 .. 32767
    int rid = cell & 31;
    int gid = (cell >> 5) & 31;
    int bid = cell >> 10;
    const float* b0 = lut + bid * 1089 + gid * 33 + rid;
    uint4 q[4];
    __half* h = (__half*)q;
#pragma unroll
    for (int k = 0; k < 8; ++k) {
        int off = (k >> 2) * 1089 + ((k >> 1) & 1) * 33 + (k & 1);
        h[k * 4 + 0] = __float2half(b0[off]);
        h[k * 4 + 1] = __float2half(b0[LUT_C + off]);
        h[k * 4 + 2] = __float2half(b0[2 * LUT_C + off]);
        h[k * 4 + 3] = __float2half(0.0f);
    }
    uint4* dst = T + (size_t)cell * 4;
    dst[0] = q[0]; dst[1] = q[1]; dst[2] = q[2]; dst[3] = q[3];
}

__device__ __forceinline__ void acc_chunk(const uint4& q, float wA, float wB,
                                          float& aR, float& aG, float& aB) {
    const __half* h = (const __half*)&q;
    aR = fmaf(wA, __half2float(h[0]), fmaf(wB, __half2float(h[4]), aR));
    aG = fmaf(wA, __half2float(h[1]), fmaf(wB, __half2float(h[5]), aG));
    aB = fmaf(wA, __half2float(h[2]), fmaf(wB, __half2float(h[6]), aB));
}

__global__ __launch_bounds__(256) void apply_lut(const float* __restrict__ x,
                                                 const __half* __restrict__ T,
                                                 float* __restrict__ out) {
    const float inv = (float)(1.0 / (1.000001 / 32.0));
    int n  = blockIdx.y;
    int i4 = blockIdx.x * blockDim.x + threadIdx.x;
    size_t base = (size_t)n * 3 * P_PLANE + (size_t)i4 * 4;

    float4 r4 = *(const float4*)(x + base);
    float4 g4 = *(const float4*)(x + base + P_PLANE);
    float4 b4 = *(const float4*)(x + base + 2 * P_PLANE);

    float r[4] = {r4.x, r4.y, r4.z, r4.w};
    float g[4] = {g4.x, g4.y, g4.z, g4.w};
    float b[4] = {b4.x, b4.y, b4.z, b4.w};
    float oR[4], oG[4], oB[4];

#pragma unroll
    for (int i = 0; i < 4; ++i) {
        float tr = r[i] * inv;
        float tg = g[i] * inv;
        float tb = b[i] * inv;
        float fr_ = floorf(tr), fg_ = floorf(tg), fb_ = floorf(tb);
        float fr = tr - fr_, fg = tg - fg_, fb = tb - fb_;
        int ri = min(max((int)fr_, 0), 31);
        int gi = min(max((int)fg_, 0), 31);
        int bi = min(max((int)fb_, 0), 31);

        const uint4* cp = (const uint4*)(T + ((size_t)(((bi << 5) | gi) << 5 | ri) << 5));
        uint4 q0 = cp[0], q1 = cp[1], q2 = cp[2], q3 = cp[3];

        float wr1 = fr, wr0 = 1.0f - fr;
        float wg1 = fg, wg0 = 1.0f - fg;
        float wb1 = fb, wb0 = 1.0f - fb;
        float w00 = wb0 * wg0, w01 = wb0 * wg1, w10 = wb1 * wg0, w11 = wb1 * wg1;

        float aR = 0.f, aG = 0.f, aB = 0.f;
        acc_chunk(q0, w00 * wr0, w00 * wr1, aR, aG, aB);
        acc_chunk(q1, w01 * wr0, w01 * wr1, aR, aG, aB);
        acc_chunk(q2, w10 * wr0, w10 * wr1, aR, aG, aB);
        acc_chunk(q3, w11 * wr0, w11 * wr1, aR, aG, aB);

        oR[i] = aR; oG[i] = aG; oB[i] = aB;
    }

    *(float4*)(out + base)               = make_float4(oR[0], oR[1], oR[2], oR[3]);
    *(float4*)(out + base + P_PLANE)     = make_float4(oG[0], oG[1], oG[2], oG[3]);
    *(float4*)(out + base + 2 * P_PLANE) = make_float4(oB[0], oB[1], oB[2], oB[3]);
}

extern "C" void kernel_launch(void* const* d_in, const int* in_sizes, int n_in,
                              void* d_out, int out_size, void* d_ws, size_t ws_size,
                              hipStream_t stream) {
    const float* lut = (const float*)d_in[0];
    const float* x   = (const float*)d_in[1];
    float* out = (float*)d_out;

    // Capture-safe host-side queries (execute immediately, not stream ops).
    int dev = 0;
    (void)hipGetDevice(&dev);
    int max_shm = 0;
    (void)hipDeviceGetAttribute(&max_shm, hipDeviceAttributeMaxSharedMemoryPerBlock, dev);
    static_assert(SMEM_BYTES == 143748, "lut lds size");
    (void)hipFuncSetAttribute((const void*)apply_lut_lds,
                              hipFuncAttributeMaxDynamicSharedMemorySize, SMEM_BYTES);

    if (max_shm >= SMEM_BYTES && ws_size >= (size_t)SMEM_BYTES) {
        // LDS-resident linear u8 table; 256 persistent blocks x 1024 threads
        // (1 block/CU, LDS-capped), 2-deep ping-pong pipeline.
        unsigned int* T = (unsigned int*)d_ws;
        build_lin_u8<<<(LUT_C + 255) / 256, 256, 0, stream>>>(lut, T);
        apply_lut_lds<<<256, 1024, SMEM_BYTES, stream>>>(x, T, out);
    } else {
        __half* T = (__half*)d_ws;
        build_table<<<128, 256, 0, stream>>>(lut, (uint4*)T);
        apply_lut<<<dim3(P_PLANE / (4 * 256), N_IMG), 256, 0, stream>>>(x, T, out);
    }
}